// Round 7
// baseline (238.536 us; speedup 1.0000x reference)
//
#include <hip/hip_runtime.h>
#include <hip/hip_bf16.h>

#define Bz 4
#define Sz 2048
#define Dz 1024
#define Hz 16
#define DHz 64
#define Mz (Bz*Sz)      // 8192
#define N3z (3*Dz)      // 3072
#define Kz Dz           // 1024

typedef short s16x8 __attribute__((ext_vector_type(8)));
typedef float f32x4 __attribute__((ext_vector_type(4)));
typedef unsigned short u16;

__device__ __forceinline__ u16 f2b(float f) {
  union { float f; unsigned u; } v; v.f = f;
  unsigned r = v.u + 0x7FFFu + ((v.u >> 16) & 1u);
  return (u16)(r >> 16);
}

__device__ __forceinline__ unsigned cvt_pk_bf16(float lo, float hi) {
  unsigned r;
  asm("v_cvt_pk_bf16_f32 %0, %1, %2" : "=v"(r) : "v"(lo), "v"(hi));
  return r;
}

// ---------------- x (f32) -> bf16, linear ----------------
__global__ __launch_bounds__(256) void cvt_x(const float* __restrict__ x,
                                             u16* __restrict__ xb) {
  int i = (blockIdx.x * 256 + threadIdx.x) * 4;
  float4 v = *reinterpret_cast<const float4*>(x + i);
  ushort4 o;
  o.x = f2b(v.x); o.y = f2b(v.y); o.z = f2b(v.z); o.w = f2b(v.w);
  *reinterpret_cast<ushort4*>(xb + i) = o;
}

// ---------------- W [K][3D] f32 -> Wt [3D][K] bf16 ----------------
__global__ __launch_bounds__(256) void transpose_w(const float* __restrict__ W,
                                                   u16* __restrict__ Wt) {
  __shared__ u16 t[32][33];
  int nb = blockIdx.x;
  int kb = blockIdx.y;
  int tx = threadIdx.x, ty = threadIdx.y;
#pragma unroll
  for (int j = 0; j < 4; ++j) {
    int k = kb * 32 + ty + j * 8;
    t[ty + j * 8][tx] = f2b(W[(size_t)k * N3z + nb * 32 + tx]);
  }
  __syncthreads();
#pragma unroll
  for (int j = 0; j < 4; ++j) {
    int n = nb * 32 + ty + j * 8;
    Wt[(size_t)n * Kz + kb * 32 + tx] = t[tx][ty + j * 8];
  }
}

// ---------------- QKV GEMM: [8192,1024] x [1024,3072] + bias ----------------
// BK=64 (half the barrier-drains of BK=32); T2 swizzle on LDS tiles:
// linear gload_lds dest + PRE-SWIZZLED global source (off = (slot^row&7)*16B),
// frag reads XOR the same pattern -> 2-way (free) instead of 16-way conflicts.
#define BM 128
#define BN 128
#define BKs 64
#define QSCALE (0.125f * 1.44269504088896f)   // 1/sqrt(64) * log2(e): exp2-domain

__global__ __launch_bounds__(256) void qkv_gemm(
    const u16* __restrict__ A, const u16* __restrict__ Bt,
    const float* __restrict__ bias,
    u16* __restrict__ Qo, u16* __restrict__ Ko, u16* __restrict__ Vo) {
  __shared__ alignas(16) u16 As[BM * BKs];   // 16 KB
  __shared__ alignas(16) u16 Bs[BN * BKs];   // 16 KB
  const int tid = threadIdx.x;
  const int wid = tid >> 6, lane = tid & 63;
  const int wr = wid >> 1, wc = wid & 1;
  const int g = lane >> 4, lq = lane & 15;
  const int brow = blockIdx.x * BM;
  const int bcol = blockIdx.y * BN;

  // staging: chunk = 8 rows x 128B; lane covers row (lane>>3), slot (lane&7).
  // source pre-swizzle: global slot = (lane&7) ^ (row&7), row&7 == lane>>3.
  const int soff = (((lane & 7) ^ (lane >> 3))) * 8;

  f32x4 acc[4][4] = {};

  for (int kt = 0; kt < Kz; kt += BKs) {
#pragma unroll
    for (int c = 0; c < 4; ++c) {
      int row = (wid * 4 + c) * 8 + (lane >> 3);
      const u16* ga = A + (size_t)(brow + row) * Kz + kt + soff;
      __builtin_amdgcn_global_load_lds(
          (const __attribute__((address_space(1))) void*)ga,
          (__attribute__((address_space(3))) void*)&As[(wid * 4 + c) * 512],
          16, 0, 0);
      const u16* gb = Bt + (size_t)(bcol + row) * Kz + kt + soff;
      __builtin_amdgcn_global_load_lds(
          (const __attribute__((address_space(1))) void*)gb,
          (__attribute__((address_space(3))) void*)&Bs[(wid * 4 + c) * 512],
          16, 0, 0);
    }
    __syncthreads();

#pragma unroll
    for (int ks = 0; ks < 2; ++ks) {
      s16x8 af[4], bfr[4];
#pragma unroll
      for (int i = 0; i < 4; ++i) {
        int rowa = wr * 64 + i * 16 + lq;
        int rowb = wc * 64 + i * 16 + lq;
        int sl = ((ks * 4 + g) ^ (lq & 7)) << 4;   // row&7 == lq&7
        af[i]  = *reinterpret_cast<const s16x8*>((const char*)As + rowa * 128 + sl);
        bfr[i] = *reinterpret_cast<const s16x8*>((const char*)Bs + rowb * 128 + sl);
      }
#pragma unroll
      for (int mi = 0; mi < 4; ++mi)
#pragma unroll
        for (int ni = 0; ni < 4; ++ni)
          acc[mi][ni] = __builtin_amdgcn_mfma_f32_16x16x32_bf16(af[mi], bfr[ni], acc[mi][ni], 0, 0, 0);
    }
    __syncthreads();
  }

#pragma unroll
  for (int ni = 0; ni < 4; ++ni) {
    int gcol = bcol + wc * 64 + ni * 16 + lq;
    int h = gcol / 192;
    int rem = gcol - h * 192;
    int tt = rem >> 6;
    int dh = rem & 63;
    float bv = bias[gcol];
    u16* dst = (tt == 0) ? Qo : (tt == 1) ? Ko : Vo;
    float scale = (tt == 0) ? QSCALE : 1.0f;
#pragma unroll
    for (int mi = 0; mi < 4; ++mi) {
#pragma unroll
      for (int r = 0; r < 4; ++r) {
        int grow = brow + wr * 64 + mi * 16 + g * 4 + r;
        int bb = grow >> 11;
        int ss = grow & 2047;
        float v = (acc[mi][ni][r] + bv) * scale;
        dst[(((size_t)bb * Hz + h) * Sz + ss) * DHz + dh] = f2b(v);
      }
    }
  }
}

// ---------------- causal flash attention ----------------
// grid (8 qpairs, 64 bh), 512 thr = 8 waves; block does q-tiles qp and 15-qp
// (perfect causal balance). Swapped QK^T + in-register softmax (T12),
// exp2 domain, defer-max (T13). T14 async-STAGE with K/V double-buffer:
// per tile { glob_load(t+1)->regs; compute(t) on buf[cur]; ds_write(t+1)->
// buf[cur^1]; ONE __syncthreads }. WAR on buf[cur^1] is covered by the
// previous iteration's barrier (all reads of that buf completed before it).
__global__ __launch_bounds__(512, 4) void attn_kernel(
    const u16* __restrict__ Qg, const u16* __restrict__ Kg,
    const u16* __restrict__ Vg, float* __restrict__ out) {
  __shared__ alignas(16) u16 Ks[2][64 * 64];      // 2 x 8 KB, swizzled
  __shared__ alignas(16) u16 Vs[2][64 * 64];      // 2 x 8 KB, V^T, swizzled

  const int qpair = blockIdx.x;
  const int bh = blockIdx.y;
  const int tid = threadIdx.x;
  const int wid = tid >> 6, lane = tid & 63;
  const int g = lane >> 4, lq = lane & 15;
  const size_t base = (size_t)bh * Sz * DHz;
  const int b = bh >> 4, h = bh & 15;

  const int krow = tid >> 3;
  const int kslot = tid & 7;
  const int kswz = kslot ^ (krow & 7);
  const int vkey = tid & 63;
  const int vdh0 = (tid >> 6) * 8;

  // P-redistribution geometry (round-5-verified)
  const int p = g & 1;
  const int cb = g >> 1;
  const int sA = 32 * (g & 1) + lq;
  const int sB = sA + 16;
  const int sEven = cb ? sB : sA;
  const int sOdd  = cb ? sA : sB;

  for (int half = 0; half < 2; ++half) {
    const int qt = half ? (15 - qpair) : qpair;
    const int q0w = qt * 128 + wid * 16;
    const int qrow = q0w + lq;

    s16x8 qf0 = *reinterpret_cast<const s16x8*>(Qg + base + (size_t)(q0w + lq) * DHz + g * 8);
    s16x8 qf1 = *reinterpret_cast<const s16x8*>(Qg + base + (size_t)(q0w + lq) * DHz + g * 8 + 32);

    f32x4 o[4] = {};
    float m1 = -1e30f;
    float l1 = 0.f;

    const int nt = 2 * qt + 2;

    // ---- prologue: stage tile 0 into buf 0 ----
    {
      s16x8 kc = *reinterpret_cast<const s16x8*>(Kg + base + (size_t)krow * DHz + kslot * 8);
      s16x8 vc = *reinterpret_cast<const s16x8*>(Vg + base + (size_t)vkey * DHz + vdh0);
      char* KB = (char*)Ks[0];
      char* VB = (char*)Vs[0];
      *reinterpret_cast<s16x8*>(KB + krow * 128 + kswz * 16) = kc;
#pragma unroll
      for (int j = 0; j < 8; ++j)
        *reinterpret_cast<u16*>(VB + (((vdh0 + j) * 128 + vkey * 2) ^ (j << 4))) = (u16)vc[j];
    }
    __syncthreads();

    int cur = 0;
    for (int t = 0; t < nt; ++t) {
      const int kv0 = t * 64;
      const bool more = (t + 1 < nt);

      // ---- issue next-tile global loads EARLY (latency hides under compute) ----
      s16x8 kn, vn;
      if (more) {
        const int nv0 = kv0 + 64;
        kn = *reinterpret_cast<const s16x8*>(Kg + base + (size_t)(nv0 + krow) * DHz + kslot * 8);
        vn = *reinterpret_cast<const s16x8*>(Vg + base + (size_t)(nv0 + vkey) * DHz + vdh0);
      }

      const char* KsC = (const char*)Ks[0] + cur * 8192;
      const char* VsC = (const char*)Vs[0] + cur * 8192;

      const bool active = (kv0 <= q0w + 15);
      if (active) {
        // ---- swapped QK^T: z[f][r] = S[q=lq][key=kv0+f*16+g*4+r] ----
        f32x4 z[4];
#pragma unroll
        for (int f = 0; f < 4; ++f) {
          int row = f * 16 + lq;
          s16x8 kb0 = *reinterpret_cast<const s16x8*>(KsC + row * 128 + ((g ^ (row & 7)) << 4));
          s16x8 kb1 = *reinterpret_cast<const s16x8*>(KsC + row * 128 + (((g + 4) ^ (row & 7)) << 4));
          f32x4 zz = {0.f, 0.f, 0.f, 0.f};
          zz = __builtin_amdgcn_mfma_f32_16x16x32_bf16(kb0, qf0, zz, 0, 0, 0);
          zz = __builtin_amdgcn_mfma_f32_16x16x32_bf16(kb1, qf1, zz, 0, 0, 0);
          z[f] = zz;
        }

        if (kv0 + 63 > q0w) {  // diagonal tile: causal mask (key > q)
#pragma unroll
          for (int f = 0; f < 4; ++f)
#pragma unroll
            for (int r = 0; r < 4; ++r) {
              int key = kv0 + f * 16 + g * 4 + r;
              if (key > qrow) z[f][r] = -1e30f;
            }
        }

        // ---- row max ----
        float pm = z[0][0];
#pragma unroll
        for (int f = 0; f < 4; ++f)
#pragma unroll
          for (int r = 0; r < 4; ++r) pm = fmaxf(pm, z[f][r]);
        pm = fmaxf(pm, __shfl_xor(pm, 16));
        pm = fmaxf(pm, __shfl_xor(pm, 32));

        // ---- T13 defer-max ----
        if (!__all(pm <= m1 + 8.0f)) {
          float mn = fmaxf(m1, pm);
          float a = exp2f(m1 - mn);
          m1 = mn;
          l1 *= a;
          float a0 = __shfl(a, 4 * g + 0);
          float a1 = __shfl(a, 4 * g + 1);
          float a2 = __shfl(a, 4 * g + 2);
          float a3 = __shfl(a, 4 * g + 3);
#pragma unroll
          for (int ni = 0; ni < 4; ++ni) {
            o[ni][0] *= a0; o[ni][1] *= a1; o[ni][2] *= a2; o[ni][3] *= a3;
          }
        }

        // ---- p = exp2(z - m), sum, pack ----
        float s = 0.f;
        unsigned w[4][2];
#pragma unroll
        for (int f = 0; f < 4; ++f) {
          float p0 = exp2f(z[f][0] - m1);
          float p1 = exp2f(z[f][1] - m1);
          float p2 = exp2f(z[f][2] - m1);
          float p3 = exp2f(z[f][3] - m1);
          s += (p0 + p1) + (p2 + p3);
          w[f][0] = cvt_pk_bf16(p0, p1);
          w[f][1] = cvt_pk_bf16(p2, p3);
        }
        s += __shfl_xor(s, 16);
        s += __shfl_xor(s, 32);
        l1 += s;

        // ---- redistribute P into PV A-fragments: 8 paired shfls ----
        int e0 = __shfl((int)(p ? w[1][0] : w[0][0]), sEven);
        int o0 = __shfl((int)(p ? w[0][0] : w[1][0]), sOdd);
        int e1 = __shfl((int)(p ? w[1][1] : w[0][1]), sEven);
        int o1 = __shfl((int)(p ? w[0][1] : w[1][1]), sOdd);
        int e2 = __shfl((int)(p ? w[3][0] : w[2][0]), sEven);
        int o2 = __shfl((int)(p ? w[2][0] : w[3][0]), sOdd);
        int e3 = __shfl((int)(p ? w[3][1] : w[2][1]), sEven);
        int o3 = __shfl((int)(p ? w[2][1] : w[3][1]), sOdd);
        union { int i[4]; s16x8 v; } A0, A1;
        A0.i[0] = cb ? o0 : e0;
        A0.i[2] = cb ? e0 : o0;
        A0.i[1] = cb ? o1 : e1;
        A0.i[3] = cb ? e1 : o1;
        A1.i[0] = cb ? o2 : e2;
        A1.i[2] = cb ? e2 : o2;
        A1.i[1] = cb ? o3 : e3;
        A1.i[3] = cb ? e3 : o3;

        // ---- PV ----
#pragma unroll
        for (int ni = 0; ni < 4; ++ni) {
          int row = ni * 16 + lq;
          s16x8 vb0 = *reinterpret_cast<const s16x8*>(VsC + row * 128 + ((g ^ (row & 7)) << 4));
          s16x8 vb1 = *reinterpret_cast<const s16x8*>(VsC + row * 128 + (((g + 4) ^ (row & 7)) << 4));
          o[ni] = __builtin_amdgcn_mfma_f32_16x16x32_bf16(A0.v, vb0, o[ni], 0, 0, 0);
          o[ni] = __builtin_amdgcn_mfma_f32_16x16x32_bf16(A1.v, vb1, o[ni], 0, 0, 0);
        }
      }

      // ---- write next tile into the other buffer, then single barrier ----
      if (more) {
        char* KB = (char*)Ks[0] + (cur ^ 1) * 8192;
        char* VB = (char*)Vs[0] + (cur ^ 1) * 8192;
        *reinterpret_cast<s16x8*>(KB + krow * 128 + kswz * 16) = kn;
#pragma unroll
        for (int j = 0; j < 8; ++j)
          *reinterpret_cast<u16*>(VB + (((vdh0 + j) * 128 + vkey * 2) ^ (j << 4))) = (u16)vn[j];
      }
      __syncthreads();
      cur ^= 1;
    }

    // ---- write out [B][S][H][DH] f32 ----
    float lr0 = __shfl(l1, 4 * g + 0);
    float lr1 = __shfl(l1, 4 * g + 1);
    float lr2 = __shfl(l1, 4 * g + 2);
    float lr3 = __shfl(l1, 4 * g + 3);
    float inv[4] = {1.0f / lr0, 1.0f / lr1, 1.0f / lr2, 1.0f / lr3};
#pragma unroll
    for (int r = 0; r < 4; ++r) {
      int s = q0w + g * 4 + r;
      float* op = out + (((size_t)b * Sz + s) * Hz + h) * DHz;
#pragma unroll
      for (int ni = 0; ni < 4; ++ni)
        op[ni * 16 + lq] = o[ni][r] * inv[r];
    }
  }
}

extern "C" void kernel_launch(void* const* d_in, const int* in_sizes, int n_in,
                              void* d_out, int out_size, void* d_ws, size_t ws_size,
                              hipStream_t stream) {
  const float* x    = (const float*)d_in[0];
  const float* W    = (const float*)d_in[1];
  const float* bias = (const float*)d_in[2];
  float* out = (float*)d_out;

  char* ws = (char*)d_ws;
  u16* xb = (u16*)(ws);                      // 16 MB
  u16* wt = (u16*)(ws + 16777216);           // 6 MB
  u16* Qb = (u16*)(ws + 23068672);           // 16 MB
  u16* Kb = (u16*)(ws + 39845888);           // 16 MB
  u16* Vb = (u16*)(ws + 56623104);           // 16 MB

  cvt_x<<<8192, 256, 0, stream>>>(x, xb);
  transpose_w<<<dim3(96, 32), dim3(32, 8), 0, stream>>>(W, wt);
  qkv_gemm<<<dim3(Mz / BM, N3z / BN), 256, 0, stream>>>(xb, wt, bias, Qb, Kb, Vb);
  attn_kernel<<<dim3(8, Bz * Hz), 512, 0, stream>>>(Qb, Kb, Vb, out);
}